// Round 16
// baseline (156.165 us; speedup 1.0000x reference)
//
#include <hip/hip_runtime.h>

// SelfAttention: B=4, S=2048, D=1024, fp32 in/out. bf16 MFMA, fp32 accum.
// R16: co-residency experiment. qkproj/sc8 move to tile 256x128, BK=32,
// 48KiB LDS, grid 512 -> TRUE 2 blocks/CU co-resident (every prior GEOM0/1
// config was 1 block/CU lockstep; cross-block overlap (m114) never tested
// with adequate phase content). Phase: reads(8) -> stage(24KB) -> barrier ->
// 16 MFMA -> vmcnt(0) -> barrier (R10-proven order; R4 showed vmcnt depth
// doesn't matter). vproj/pv8 unchanged (pv8 rowpart loop 8->16).
//   qkproj: corew 256x128, grid 512 (Q and K)
//   vproj:  core2g1 128x256, grid 256 (Vt transposed)
//   sc:     corew 256x128, grid 512, P~=exp(QK^T/32)+rowsums (16 col-tiles)
//   pv:     core2g1 128x256, grid 256, * 1/rowsum (in-kernel rsum, 16 parts)
// ws layout (MiB):
//   [0,16)   x_bf16 (proj) -> P~ bf16 [4][2048][2048]
//   [16,32)  Q bf16   [32,48) K bf16   [48,64) Vt bf16 [4][1024][2048]
//   [64,70)  Wq|Wk|Wv bf16
//   [70,+512K) rowpart fp32 [16][4][2048]

typedef __bf16 bf16x8 __attribute__((ext_vector_type(8)));
typedef float f32x4 __attribute__((ext_vector_type(4)));
typedef unsigned short u16;

__device__ __forceinline__ u16 f2b(float f) {
  union { float f; unsigned u; } a; a.f = f;
  unsigned r = a.u + 0x7fffu + ((a.u >> 16) & 1u);  // RNE
  return (u16)(r >> 16);
}

__device__ __forceinline__ int xcd_swz256(int p) { return (p & 7) * 32 + (p >> 3); }
__device__ __forceinline__ int xcd_swz512(int p) { return (p & 7) * 64 + (p >> 3); }

// blocks [0,8192): x (2097152 float4s). blocks [8192,11264): Wq|Wk|Wv.
__global__ __launch_bounds__(256) void cast_all_kernel(const float* __restrict__ x,
                                                       const float* __restrict__ Wq,
                                                       const float* __restrict__ Wk,
                                                       const float* __restrict__ Wv,
                                                       u16* __restrict__ xb,
                                                       u16* __restrict__ Wb) {
  int b = blockIdx.x;
  if (b < 8192) {
    const int i = b * 256 + threadIdx.x;
    float4 v = reinterpret_cast<const float4*>(x)[i];
    reinterpret_cast<ushort4*>(xb)[i] =
        make_ushort4(f2b(v.x), f2b(v.y), f2b(v.z), f2b(v.w));
  } else {
    b -= 8192;
    const int w = b >> 10;
    const float* src = (w == 0) ? Wq : (w == 1) ? Wk : Wv;
    const int i = (b & 1023) * 256 + threadIdx.x;
    float4 v = reinterpret_cast<const float4*>(src)[i];
    reinterpret_cast<ushort4*>(Wb + (size_t)w * 1048576)[i] =
        make_ushort4(f2b(v.x), f2b(v.y), f2b(v.z), f2b(v.w));
  }
}

// ---------------- R16 co-resident core: tile 256x128, BK=32, 48KiB LDS ----------------
// 8 waves: wr=wave>>1 (4 M-quads of 64 rows), wc=wave&1 (2 N-halves of 64).
// Wave tile 64x64 -> 16 MFMA + 8 ds_read_b128 per phase. NT = K/32 phases.
// LDS buf (24576 B): A [0,16K) 16 subtiles, B [16K,24K) 8 subtiles. 2 bufs.
template <int NT>
__device__ __forceinline__ void corew(const char* __restrict__ Ab,
                                      const char* __restrict__ Bb, int lda, int ldb,
                                      char* smem, f32x4* acc) {
  const int tid = threadIdx.x;
  const int wave = tid >> 6, lane = tid & 63;
  const int wr = wave >> 1, wc = wave & 1;
  const int fr = lane & 15, fg = lane >> 4;
  const int rd = (fr * 64 + fg * 16) ^ (((fr >> 3) & 1) << 5);
  const int li = (lane * 16) ^ ((lane >> 5) << 5);
  const int sr = li >> 6, sc2 = li & 63;

  auto STAGE = [&](int kt) {  // full K-step tile: A 16KB + B 8KB (3 loads/wave)
    char* base = smem + (kt & 1) * 24576;
    const int colOff = kt * 64 + sc2;
    __builtin_amdgcn_global_load_lds(
        (const __attribute__((address_space(1))) void*)(Ab + (size_t)(wave * 16 + sr) * lda + colOff),
        (__attribute__((address_space(3))) void*)(base + wave * 1024), 16, 0, 0);
    __builtin_amdgcn_global_load_lds(
        (const __attribute__((address_space(1))) void*)(Ab + (size_t)((8 + wave) * 16 + sr) * lda + colOff),
        (__attribute__((address_space(3))) void*)(base + 8192 + wave * 1024), 16, 0, 0);
    __builtin_amdgcn_global_load_lds(
        (const __attribute__((address_space(1))) void*)(Bb + (size_t)(wave * 16 + sr) * ldb + colOff),
        (__attribute__((address_space(3))) void*)(base + 16384 + wave * 1024), 16, 0, 0);
  };

  STAGE(0);
  asm volatile("s_waitcnt vmcnt(0)" ::: "memory");
  __builtin_amdgcn_s_barrier();
  __builtin_amdgcn_sched_barrier(0);

  for (int kt = 0; kt < NT; ++kt) {
    const char* bufA = smem + (kt & 1) * 24576;
    const char* bufB = bufA + 16384;
    bf16x8 afr[4], bfr[4];
#pragma unroll
    for (int m = 0; m < 4; ++m)
      afr[m] = *reinterpret_cast<const bf16x8*>(bufA + (wr * 4 + m) * 1024 + rd);
#pragma unroll
    for (int n = 0; n < 4; ++n)
      bfr[n] = *reinterpret_cast<const bf16x8*>(bufB + (wc * 4 + n) * 1024 + rd);
    if (kt + 1 < NT) STAGE(kt + 1);
    __builtin_amdgcn_s_barrier();
    __builtin_amdgcn_sched_barrier(0);
    __builtin_amdgcn_s_setprio(1);
#pragma unroll
    for (int m = 0; m < 4; ++m)
#pragma unroll
      for (int n = 0; n < 4; ++n)
        acc[m * 4 + n] = __builtin_amdgcn_mfma_f32_16x16x32_bf16(
            afr[m], bfr[n], acc[m * 4 + n], 0, 0, 0);
    __builtin_amdgcn_s_setprio(0);
    if (kt + 1 < NT) asm volatile("s_waitcnt vmcnt(0)" ::: "memory");
    __builtin_amdgcn_s_barrier();
    __builtin_amdgcn_sched_barrier(0);
  }
}

// ---------------- merged-phase core (GEOM1 kernels; R7/R10 validated) ----------------
template <int NT>
__device__ __forceinline__ void core2g1(const char* __restrict__ Ab,
                                        const char* __restrict__ Bb, int lda, int ldb,
                                        char* smem, f32x4* acc) {
  const int tid = threadIdx.x;
  const int wave = tid >> 6, lane = tid & 63;
  const int wr = wave >> 2, wc = wave & 3;
  const int fr = lane & 15, fg = lane >> 4;
  const int rd = (fr * 64 + fg * 16) ^ (((fr >> 3) & 1) << 5);
  const int li = (lane * 16) ^ ((lane >> 5) << 5);
  const int sr = li >> 6, sc2 = li & 63;

  auto STAGE = [&](int kt, int s) {
    char* base = smem + (kt & 1) * 49152;
    const int colOff = kt * 128 + s * 64 + sc2;
    char* ldsA = base + s * 8192;
    __builtin_amdgcn_global_load_lds(
        (const __attribute__((address_space(1))) void*)(Ab + (size_t)(wave * 16 + sr) * lda + colOff),
        (__attribute__((address_space(3))) void*)(ldsA + wave * 1024), 16, 0, 0);
    char* ldsB = base + 16384 + s * 16384;
    __builtin_amdgcn_global_load_lds(
        (const __attribute__((address_space(1))) void*)(Bb + (size_t)(wave * 16 + sr) * ldb + colOff),
        (__attribute__((address_space(3))) void*)(ldsB + wave * 1024), 16, 0, 0);
    __builtin_amdgcn_global_load_lds(
        (const __attribute__((address_space(1))) void*)(Bb + (size_t)((8 + wave) * 16 + sr) * ldb + colOff),
        (__attribute__((address_space(3))) void*)(ldsB + 8192 + wave * 1024), 16, 0, 0);
  };

  STAGE(0, 0);
  STAGE(0, 1);
  asm volatile("s_waitcnt vmcnt(3)" ::: "memory");
  __builtin_amdgcn_s_barrier();
  __builtin_amdgcn_sched_barrier(0);

  for (int kt = 0; kt < NT; ++kt) {
    const char* bufA = smem + (kt & 1) * 49152;
    const char* bufB = bufA + 16384;
#pragma unroll
    for (int s = 0; s < 2; ++s) {
      bf16x8 afr[4], bfr[4];
#pragma unroll
      for (int m = 0; m < 4; ++m)
        afr[m] = *reinterpret_cast<const bf16x8*>(bufA + s * 8192 + (wr * 4 + m) * 1024 + rd);
#pragma unroll
      for (int n = 0; n < 4; ++n)
        bfr[n] = *reinterpret_cast<const bf16x8*>(bufB + s * 16384 + (wc * 4 + n) * 1024 + rd);
      if (kt + 1 < NT) STAGE(kt + 1, s);
      __builtin_amdgcn_s_barrier();
      __builtin_amdgcn_sched_barrier(0);
      __builtin_amdgcn_s_setprio(1);
#pragma unroll
      for (int m = 0; m < 4; ++m)
#pragma unroll
        for (int n = 0; n < 4; ++n)
          acc[m * 4 + n] = __builtin_amdgcn_mfma_f32_16x16x32_bf16(
              afr[m], bfr[n], acc[m * 4 + n], 0, 0, 0);
      __builtin_amdgcn_s_setprio(0);
      if (kt < NT - 1) {
        asm volatile("s_waitcnt vmcnt(3)" ::: "memory");
      } else if (s == 0) {
        asm volatile("s_waitcnt vmcnt(0)" ::: "memory");
      }
      __builtin_amdgcn_s_barrier();
      __builtin_amdgcn_sched_barrier(0);
    }
  }
}

// ---------------- QK projection: corew 256x128, grid 512 (swizzled) ----------------
// A = xb [8192][1024], B = Wb[Wq|Wk] [2048][1024]. by 0..15 (128-col tiles).
__global__ __launch_bounds__(512, 2) void qkproj_kernel(
    const u16* __restrict__ A, const u16* __restrict__ Bm,
    const float* __restrict__ bq, const float* __restrict__ bk,
    u16* __restrict__ QK) {
  extern __shared__ char smem[];  // 49152
  const int wk = xcd_swz512(blockIdx.x);
  const int bx = wk >> 4, by = wk & 15;  // (32, 16)
  const int tileM = bx * 256, tileN = by * 128;
  f32x4 acc[16] = {};
  corew<32>((const char*)A + (size_t)tileM * 2048,
            (const char*)Bm + (size_t)tileN * 2048, 2048, 2048, smem, acc);
  const int tid = threadIdx.x;
  const int wave = tid >> 6, lane = tid & 63;
  const int wr = wave >> 1, wc = wave & 1, fr = lane & 15, fg = lane >> 4;
  const int w = by >> 3;  // 0 -> Q, 1 -> K (128-col tiles never straddle)
  const float* bias = (w == 0) ? bq : bk;
  u16* O = QK + (size_t)w * 8388608;
#pragma unroll
  for (int mi = 0; mi < 4; ++mi) {
    const int r0 = tileM + wr * 64 + mi * 16 + fg * 4;
#pragma unroll
    for (int n = 0; n < 4; ++n) {
      const int cw = (tileN + wc * 64 + n * 16 + fr) & 1023;
      const float bi = bias[cw];
#pragma unroll
      for (int jj = 0; jj < 4; ++jj)
        O[(size_t)(r0 + jj) * 1024 + cw] = f2b(acc[mi * 4 + n][jj] + bi);
    }
  }
}

// ---------------- V projection: core2g1 128x256, 256 blocks (swizzled) ----------------
__global__ __launch_bounds__(512, 2) void vproj_kernel(
    const u16* __restrict__ A, const u16* __restrict__ Bv,
    const float* __restrict__ bvv, u16* __restrict__ Vt) {
  extern __shared__ char smem[];
  const int wk = xcd_swz256(blockIdx.x);
  const int bx = wk & 63, by = wk >> 6;  // (64,4)
  const int tileM = bx * 128, tileN = by * 256;
  f32x4 acc[16] = {};
  core2g1<16>((const char*)A + (size_t)tileM * 2048,
              (const char*)Bv + (size_t)tileN * 2048, 2048, 2048, smem, acc);
  const int tid = threadIdx.x;
  const int wave = tid >> 6, lane = tid & 63;
  const int wr = wave >> 2, wc = wave & 3, fr = lane & 15, fg = lane >> 4;
#pragma unroll
  for (int mi = 0; mi < 4; ++mi) {
    const int r0 = tileM + wr * 64 + mi * 16 + fg * 4;
    const int b = r0 >> 11, s0 = r0 & 2047;
#pragma unroll
    for (int n = 0; n < 4; ++n) {
      const int cw = (tileN + wc * 64 + n * 16 + fr) & 1023;
      const float bi = bvv[cw];
      ushort4 u = make_ushort4(f2b(acc[mi * 4 + n][0] + bi), f2b(acc[mi * 4 + n][1] + bi),
                               f2b(acc[mi * 4 + n][2] + bi), f2b(acc[mi * 4 + n][3] + bi));
      *reinterpret_cast<ushort4*>(&Vt[(size_t)b * 2097152 + (size_t)cw * 2048 + s0]) = u;
    }
  }
}

// ---------------- sc: corew 256x128, grid 512; P~ = exp(QK^T/32) + 16 partials ----------------
__global__ __launch_bounds__(512, 2) void sc8_kernel(const u16* __restrict__ Qb,
                                                     const u16* __restrict__ Kb,
                                                     u16* __restrict__ P,
                                                     float* __restrict__ rowpart) {
  extern __shared__ char smem[];  // 49152
  const int wk = xcd_swz512(blockIdx.x);
  const int z = wk >> 7, bx = (wk >> 4) & 7, by = wk & 15;  // (8 Mtiles, 16 Ntiles)
  const int tileM = bx * 256, tileN = by * 128;
  f32x4 acc[16] = {};
  corew<32>((const char*)Qb + (size_t)z * 4194304 + (size_t)tileM * 2048,
            (const char*)Kb + (size_t)z * 4194304 + (size_t)tileN * 2048, 2048, 2048,
            smem, acc);
  const int tid = threadIdx.x;
  const int wave = tid >> 6, lane = tid & 63;
  const int wr = wave >> 1, wc = wave & 1, fr = lane & 15, fg = lane >> 4;
  float* rs = (float*)smem;  // [2][256]; safe: corew ends with full barrier
  u16* Po = P + (size_t)z * 4194304 + (size_t)tileM * 2048 + tileN;
#pragma unroll
  for (int mi = 0; mi < 4; ++mi) {
#pragma unroll
    for (int jj = 0; jj < 4; ++jj) {
      const int rl = wr * 64 + mi * 16 + fg * 4 + jj;
      float part = 0.f;
#pragma unroll
      for (int n = 0; n < 4; ++n) {
        float e = __expf(acc[mi * 4 + n][jj] * 0.03125f);
        part += e;
        Po[(size_t)rl * 2048 + wc * 64 + n * 16 + fr] = f2b(e);
      }
      part += __shfl_xor(part, 1);
      part += __shfl_xor(part, 2);
      part += __shfl_xor(part, 4);
      part += __shfl_xor(part, 8);
      if (fr == 0) rs[wc * 256 + rl] = part;
    }
  }
  __syncthreads();
  if (tid < 256) {
    float s = rs[tid] + rs[256 + tid];
    rowpart[(size_t)by * 8192 + z * 2048 + tileM + tid] = s;
  }
}

// ---------------- pv: core2g1; out = (P~ Vt^T) * rowinv (16 partials) ----------------
__global__ __launch_bounds__(512, 2) void pv8_kernel(const u16* __restrict__ P,
                                                     const u16* __restrict__ Vt,
                                                     const float* __restrict__ rowpart,
                                                     float* __restrict__ out) {
  extern __shared__ char smem[];  // 98304 core + 512 rowinv
  const int wk = xcd_swz256(blockIdx.x);
  const int bx = wk & 15, by = (wk >> 4) & 3, z = wk >> 6;
  const int tileM = bx * 128, tileN = by * 256;
  float* rinv = (float*)(smem + 98304);
  const int tid = threadIdx.x;
  if (tid < 128) {
    float s = 0.f;
#pragma unroll
    for (int t = 0; t < 16; ++t) s += rowpart[t * 8192 + z * 2048 + tileM + tid];
    rinv[tid] = 1.0f / s;
  }
  __builtin_amdgcn_sched_barrier(0);
  f32x4 acc[16] = {};
  core2g1<32>((const char*)P + (size_t)z * 8388608 + (size_t)tileM * 4096,
              (const char*)Vt + (size_t)z * 4194304 + (size_t)tileN * 4096, 4096, 4096,
              smem, acc);
  const int wave = tid >> 6, lane = tid & 63;
  const int wr = wave >> 2, wc = wave & 3, fr = lane & 15, fg = lane >> 4;
  float* O = out + (size_t)z * 2097152;
#pragma unroll
  for (int mi = 0; mi < 4; ++mi) {
#pragma unroll
    for (int jj = 0; jj < 4; ++jj) {
      const int r = wr * 64 + mi * 16 + fg * 4 + jj;
      const float inv = rinv[r];
#pragma unroll
      for (int n = 0; n < 4; ++n)
        O[(size_t)(tileM + r) * 1024 + tileN + wc * 64 + n * 16 + fr] =
            acc[mi * 4 + n][jj] * inv;
    }
  }
}

extern "C" void kernel_launch(void* const* d_in, const int* in_sizes, int n_in,
                              void* d_out, int out_size, void* d_ws, size_t ws_size,
                              hipStream_t stream) {
  if (ws_size < ((size_t)72 << 20)) return;
  const float* x = (const float*)d_in[0];
  const float* Wq = (const float*)d_in[1];
  const float* bq = (const float*)d_in[2];
  const float* Wk = (const float*)d_in[3];
  const float* bk = (const float*)d_in[4];
  const float* Wv = (const float*)d_in[5];
  const float* bv = (const float*)d_in[6];
  char* ws = (char*)d_ws;
  u16* xb = (u16*)(ws);                       // [0,16M); later P~ [4][2048][2048]
  u16* Pb = (u16*)(ws);
  u16* Qb = (u16*)(ws + ((size_t)16 << 20));
  u16* Kb = (u16*)(ws + ((size_t)32 << 20));
  u16* Vt = (u16*)(ws + ((size_t)48 << 20));
  u16* Wb = (u16*)(ws + ((size_t)64 << 20));
  float* rowpart = (float*)(ws + ((size_t)70 << 20));  // 512 KiB
  float* out = (float*)d_out;

  (void)hipFuncSetAttribute((const void*)qkproj_kernel,
                            hipFuncAttributeMaxDynamicSharedMemorySize, 49152);
  (void)hipFuncSetAttribute((const void*)vproj_kernel,
                            hipFuncAttributeMaxDynamicSharedMemorySize, 98304);
  (void)hipFuncSetAttribute((const void*)sc8_kernel,
                            hipFuncAttributeMaxDynamicSharedMemorySize, 49152);
  (void)hipFuncSetAttribute((const void*)pv8_kernel,
                            hipFuncAttributeMaxDynamicSharedMemorySize, 98816);

  cast_all_kernel<<<11264, 256, 0, stream>>>(x, Wq, Wk, Wv, xb, Wb);

  qkproj_kernel<<<512, 512, 49152, stream>>>(xb, Wb, bq, bk, Qb);
  vproj_kernel<<<256, 512, 98304, stream>>>(xb, Wb + 2097152, bv, Vt);

  sc8_kernel<<<512, 512, 49152, stream>>>(Qb, Kb, Pb, rowpart);
  pv8_kernel<<<256, 512, 98816, stream>>>(Pb, Vt, rowpart, out);
}